// Round 8
// baseline (361.052 us; speedup 1.0000x reference)
//
#include <hip/hip_runtime.h>
#include <hip/hip_bf16.h>

// MoE top-1: N=16384 tokens, D=1024, E=8 experts.
// out[n] = expert_w[argmax(router(x[n]))] @ x[n] + expert_b[e]
//
// Pipeline: convw -> router (rw in LDS, token-pair ILP, f64 in-lane dots +
// f32 cross-lane reduce, fused x->bf16, no atomics) -> single-block counting
// sort -> grouped bf16-MFMA GEMM (dbuf LDS, counted vmcnt, raw s_barrier,
// expert->XCD swizzle).

#define NTOK 16384
#define DIM  1024
#define NEXP 8

typedef __bf16 bf16x8 __attribute__((ext_vector_type(8)));
typedef float  f32x4  __attribute__((ext_vector_type(4)));

__device__ __forceinline__ unsigned int f2bf(float f) {
  unsigned int u = __builtin_bit_cast(unsigned int, f);
  u += 0x7FFFu + ((u >> 16) & 1u);   // round-to-nearest-even (finite inputs)
  return u >> 16;
}

// expert_w f32 -> bf16, 8 elements per thread. grid 4096 x 256. Tiny VGPR,
// full occupancy (kept SEPARATE from router: kernel union inflates VGPR).
__global__ __launch_bounds__(256) void k_convw(const float* __restrict__ src,
                                               unsigned short* __restrict__ dst) {
  size_t i = ((size_t)blockIdx.x * 256 + threadIdx.x) * 8;
  const float4* p = (const float4*)(src + i);
  float4 a = p[0], b = p[1];
  unsigned int w0 = f2bf(a.x) | (f2bf(a.y) << 16);
  unsigned int w1 = f2bf(a.z) | (f2bf(a.w) << 16);
  unsigned int w2 = f2bf(b.x) | (f2bf(b.y) << 16);
  unsigned int w3 = f2bf(b.z) | (f2bf(b.w) << 16);
  *(uint4*)(dst + i) = make_uint4(w0, w1, w2, w3);
}

// Router: rw (32 KB) staged in LDS once per block. Lane l owns x elements
// {j*512 + l*8 .. +8}, j=0..1 (16 elems). TWO tokens processed per w-fragment
// read (w LDS traffic halved, two independent FMA chains). In-lane 16-term
// partials accumulate in f64 (f32 products exact => dot ground-truth);
// cross-lane reduction in f32 (error ~3e-7 << np's own f32 noise ~2e-6).
// Reduce: xor{1,2,4} on 8 partials -> static select expert lane&7 (rule #20)
// -> xor{8,16,32} -> +bias -> argmax xor{1,2,4}, first index on ties.
// Fused x->bf16 (one uint4 store per (token,j)). No atomics.
__global__ __launch_bounds__(256, 4) void k_router(const float* __restrict__ x,
                                                   const float* __restrict__ rw,
                                                   const float* __restrict__ rb,
                                                   unsigned short* __restrict__ xbf,
                                                   int* __restrict__ top) {
  __shared__ float wlds[NEXP * DIM];   // 32 KB
  const int tid = threadIdx.x;
  const int lane = tid & 63;
  const int wave = tid >> 6;
#pragma unroll
  for (int i = 0; i < 8; ++i)
    ((float4*)wlds)[tid + 256 * i] = ((const float4*)rw)[tid + 256 * i];
  __syncthreads();

  const int ea = lane & 7;
  const float bias = rb[ea];

#pragma unroll 1
  for (int tp = 0; tp < 2; ++tp) {     // two token-pairs per wave (4 tokens)
    const int nA = (blockIdx.x << 4) + (wave << 2) + (tp << 1);
    const int nB = nA + 1;

    float4 xa[2][2], xb[2][2];
#pragma unroll
    for (int j = 0; j < 2; ++j) {
      const float* pa = x + ((size_t)nA << 10) + (j << 9) + (lane << 3);
      const float* pb = x + ((size_t)nB << 10) + (j << 9) + (lane << 3);
      xa[j][0] = *(const float4*)pa;
      xa[j][1] = *(const float4*)(pa + 4);
      xb[j][0] = *(const float4*)pb;
      xb[j][1] = *(const float4*)(pb + 4);
    }

    // fused bf16 conversion + store: 16 B/lane per (token,j), coalesced 1 KB
#pragma unroll
    for (int j = 0; j < 2; ++j) {
      uint4 sa, sb;
      sa.x = f2bf(xa[j][0].x) | (f2bf(xa[j][0].y) << 16);
      sa.y = f2bf(xa[j][0].z) | (f2bf(xa[j][0].w) << 16);
      sa.z = f2bf(xa[j][1].x) | (f2bf(xa[j][1].y) << 16);
      sa.w = f2bf(xa[j][1].z) | (f2bf(xa[j][1].w) << 16);
      sb.x = f2bf(xb[j][0].x) | (f2bf(xb[j][0].y) << 16);
      sb.y = f2bf(xb[j][0].z) | (f2bf(xb[j][0].w) << 16);
      sb.z = f2bf(xb[j][1].x) | (f2bf(xb[j][1].y) << 16);
      sb.w = f2bf(xb[j][1].z) | (f2bf(xb[j][1].w) << 16);
      *(uint4*)(xbf + ((size_t)nA << 10) + (j << 9) + (lane << 3)) = sa;
      *(uint4*)(xbf + ((size_t)nB << 10) + (j << 9) + (lane << 3)) = sb;
    }

    double pA[8] = {}, pB[8] = {};
#pragma unroll
    for (int e = 0; e < 8; ++e)
#pragma unroll
      for (int j = 0; j < 2; ++j) {
        float4 w0 = *(const float4*)&wlds[e * 1024 + (j << 9) + (lane << 3)];
        float4 w1 = *(const float4*)&wlds[e * 1024 + (j << 9) + (lane << 3) + 4];
        pA[e] += (double)xa[j][0].x * (double)w0.x;
        pA[e] += (double)xa[j][0].y * (double)w0.y;
        pA[e] += (double)xa[j][0].z * (double)w0.z;
        pA[e] += (double)xa[j][0].w * (double)w0.w;
        pA[e] += (double)xa[j][1].x * (double)w1.x;
        pA[e] += (double)xa[j][1].y * (double)w1.y;
        pA[e] += (double)xa[j][1].z * (double)w1.z;
        pA[e] += (double)xa[j][1].w * (double)w1.w;
        pB[e] += (double)xb[j][0].x * (double)w0.x;
        pB[e] += (double)xb[j][0].y * (double)w0.y;
        pB[e] += (double)xb[j][0].z * (double)w0.z;
        pB[e] += (double)xb[j][0].w * (double)w0.w;
        pB[e] += (double)xb[j][1].x * (double)w1.x;
        pB[e] += (double)xb[j][1].y * (double)w1.y;
        pB[e] += (double)xb[j][1].z * (double)w1.z;
        pB[e] += (double)xb[j][1].w * (double)w1.w;
      }

    // f32 cross-lane reduce (two independent chains interleave)
    float qA[8], qB[8];
#pragma unroll
    for (int e = 0; e < 8; ++e) { qA[e] = (float)pA[e]; qB[e] = (float)pB[e]; }
#pragma unroll
    for (int e = 0; e < 8; ++e) {
      qA[e] += __shfl_xor(qA[e], 1);
      qB[e] += __shfl_xor(qB[e], 1);
      qA[e] += __shfl_xor(qA[e], 2);
      qB[e] += __shfl_xor(qB[e], 2);
      qA[e] += __shfl_xor(qA[e], 4);
      qB[e] += __shfl_xor(qB[e], 4);
    }
    // static select tree: s = q[ea] without runtime indexing (rule #20)
    float sA, sB;
    {
      float q0 = (ea & 1) ? qA[1] : qA[0], q1 = (ea & 1) ? qA[3] : qA[2];
      float q2 = (ea & 1) ? qA[5] : qA[4], q3 = (ea & 1) ? qA[7] : qA[6];
      float r0 = (ea & 2) ? q1 : q0, r1 = (ea & 2) ? q3 : q2;
      sA = (ea & 4) ? r1 : r0;
      q0 = (ea & 1) ? qB[1] : qB[0]; q1 = (ea & 1) ? qB[3] : qB[2];
      q2 = (ea & 1) ? qB[5] : qB[4]; q3 = (ea & 1) ? qB[7] : qB[6];
      r0 = (ea & 2) ? q1 : q0; r1 = (ea & 2) ? q3 : q2;
      sB = (ea & 4) ? r1 : r0;
    }
    sA += __shfl_xor(sA, 8);  sB += __shfl_xor(sB, 8);
    sA += __shfl_xor(sA, 16); sB += __shfl_xor(sB, 16);
    sA += __shfl_xor(sA, 32); sB += __shfl_xor(sB, 32);
    sA += bias; sB += bias;
    // argmax over experts (lane bits 0-2); first index on ties (np.argmax)
    float bvA = sA, bvB = sB;
    int biA = ea, biB = ea;
#pragma unroll
    for (int mask = 1; mask <= 4; mask <<= 1) {
      float ovA = __shfl_xor(bvA, mask), ovB = __shfl_xor(bvB, mask);
      int oiA = __shfl_xor(biA, mask), oiB = __shfl_xor(biB, mask);
      if (ovA > bvA || (ovA == bvA && oiA < biA)) { bvA = ovA; biA = oiA; }
      if (ovB > bvB || (ovB == bvB && oiB < biB)) { bvB = ovB; biB = oiB; }
    }
    if (lane == 0) {
      top[nA] = biA;
      top[nB] = biB;
    }
  }
}

// Counting sort of 16384 expert ids in ONE block (1024 threads x 16 tokens).
// Per-thread histogram packed as 2x u64 (8 experts x 16-bit fields); Hillis-
// Steele scan over packed u64s in LDS; ordered scatter into per-expert lists.
// Deterministic; lists sorted by token index (GEMM gather locality).
__global__ __launch_bounds__(1024) void k_sort(const int* __restrict__ top,
                                               int* __restrict__ counts,
                                               int* __restrict__ tok) {
  __shared__ unsigned long long sc[2][2][1024];  // 32 KB
  const int t = threadIdx.x;

  int4 v[4];
  const int4* tp = (const int4*)(top + t * 16);
#pragma unroll
  for (int i = 0; i < 4; ++i) v[i] = tp[i];

  unsigned long long h0 = 0, h1 = 0;
#pragma unroll
  for (int i = 0; i < 16; ++i) {
    int e = ((const int*)v)[i];
    if (e < 4) h0 += 1ull << (16 * e);
    else       h1 += 1ull << (16 * (e - 4));
  }
  sc[0][0][t] = h0;
  sc[0][1][t] = h1;
  __syncthreads();

  int cur = 0;
  for (int s = 1; s < 1024; s <<= 1) {
    unsigned long long a0 = sc[cur][0][t], a1 = sc[cur][1][t];
    if (t >= s) { a0 += sc[cur][0][t - s]; a1 += sc[cur][1][t - s]; }
    sc[cur ^ 1][0][t] = a0;
    sc[cur ^ 1][1][t] = a1;
    cur ^= 1;
    __syncthreads();
  }

  unsigned long long b0 = sc[cur][0][t] - h0;
  unsigned long long b1 = sc[cur][1][t] - h1;
  if (t == 1023) {
    unsigned long long i0 = sc[cur][0][t], i1 = sc[cur][1][t];
#pragma unroll
    for (int e = 0; e < 4; ++e) counts[e] = (int)((i0 >> (16 * e)) & 0xFFFF);
#pragma unroll
    for (int e = 0; e < 4; ++e) counts[4 + e] = (int)((i1 >> (16 * e)) & 0xFFFF);
  }
#pragma unroll
  for (int i = 0; i < 16; ++i) {
    int e = ((const int*)v)[i];
    int pos;
    if (e < 4) {
      pos = (int)((b0 >> (16 * e)) & 0xFFFF);
      b0 += 1ull << (16 * e);
    } else {
      int f = e - 4;
      pos = (int)((b1 >> (16 * f)) & 0xFFFF);
      b1 += 1ull << (16 * f);
    }
    tok[(e << 14) + pos] = t * 16 + i;
  }
}

// Grouped GEMM: C[m,o] = sum_d Xg[m,d] * W[o,d]. 128x128 tile, BK=64, 4 waves,
// mfma_f32_16x16x32_bf16. Double-buffered LDS staging with counted vmcnt and
// raw s_barrier (no vmcnt(0) drain in the main loop — T3+T4 pattern).
// 1D grid 8192, swizzled: xcd = bid&7 = expert; within an XCD, col-tile varies
// fastest so W_e (2 MB) and the current X token-tile stay L2-resident.
__global__ __launch_bounds__(256, 2) void k_gemm(const unsigned short* __restrict__ xbf,
                                                 const unsigned short* __restrict__ wbf,
                                                 const float* __restrict__ eb,
                                                 const int* __restrict__ counts,
                                                 const int* __restrict__ tokall,
                                                 float* __restrict__ out) {
  const int bid = blockIdx.x;          // 0..8191
  const int e = bid & 7;               // expert == XCD (dispatch round-robins %8)
  const int loc = bid >> 3;            // 0..1023 within XCD
  const int cb = loc & 7;              // col tile (fastest -> temporal locality)
  const int t = loc >> 3;              // token tile 0..127
  const int c = counts[e];
  if (t * 128 >= c) return;
  const int n0 = cb << 7;
  const int* tok = tokall + (e << 14);
  const int tid = threadIdx.x;
  const int lane = tid & 63;
  const int wave = tid >> 6;

  __shared__ unsigned short As[2][128 * 64];  // 2 x 16 KB, chunk-swizzled
  __shared__ unsigned short Bs[2][128 * 64];

  // Staging addresses: 4 x (32 rows x 8 chunks of 16B) per buffer. LDS dest is
  // linear (global_load_lds requirement); swizzle on the GLOBAL source side:
  // physical chunk p at row r holds logical chunk p ^ (r & 7).
  const int prow = tid >> 3;
  const int pchk = tid & 7;
  size_t asrc[4], bsrc[4];
  const unsigned short* wb = wbf + ((size_t)e << 20);
#pragma unroll
  for (int s = 0; s < 4; ++s) {
    int row = s * 32 + prow;
    int m = t * 128 + row;
    int g = tok[(m < c) ? m : 0];          // pad rows replay token 0 (stores guarded)
    int l = pchk ^ (row & 7);
    asrc[s] = (size_t)g * DIM + (size_t)l * 8;
    bsrc[s] = (size_t)(n0 + row) * DIM + (size_t)l * 8;
  }

  f32x4 acc[4][4] = {};
  const int wr = wave >> 1, wc = wave & 1;

  // LDS read offsets (elements). A-frag: lane holds A[row = lane&15][k = (lane>>4)*8 + j].
  int aoff[2][4], boff[2][4];
#pragma unroll
  for (int h = 0; h < 2; ++h)
#pragma unroll
    for (int m = 0; m < 4; ++m) {
      int row = wr * 64 + m * 16 + (lane & 15);
      int p = (h * 4 + (lane >> 4)) ^ (row & 7);
      aoff[h][m] = row * 64 + p * 8;
      int rowb = wc * 64 + m * 16 + (lane & 15);
      int pb = (h * 4 + (lane >> 4)) ^ (rowb & 7);
      boff[h][m] = rowb * 64 + pb * 8;
    }

  // stage one K-tile (8 global_load_lds of 16B per thread) into buffer b
  auto stage = [&](int b, int k0) {
#pragma unroll
    for (int s = 0; s < 4; ++s) {
      __builtin_amdgcn_global_load_lds(
          (const __attribute__((address_space(1))) unsigned int*)(xbf + asrc[s] + k0),
          (__attribute__((address_space(3))) unsigned int*)(&As[b][s * 2048 + wave * 512]),
          16, 0, 0);
      __builtin_amdgcn_global_load_lds(
          (const __attribute__((address_space(1))) unsigned int*)(wb + bsrc[s] + k0),
          (__attribute__((address_space(3))) unsigned int*)(&Bs[b][s * 2048 + wave * 512]),
          16, 0, 0);
    }
  };

  stage(0, 0);                          // 8 loads in flight
  for (int k = 0; k < 16; ++k) {
    if (k < 15) {
      stage((k + 1) & 1, (k + 1) * 64); // 16 in flight
      asm volatile("s_waitcnt vmcnt(8)" ::: "memory");  // current tile landed
    } else {
      asm volatile("s_waitcnt vmcnt(0)" ::: "memory");
    }
    __builtin_amdgcn_s_barrier();       // raw barrier: no compiler vmcnt(0) drain
    __builtin_amdgcn_sched_barrier(0);
    const unsigned short* Ab = As[k & 1];
    const unsigned short* Bb = Bs[k & 1];
#pragma unroll
    for (int h = 0; h < 2; ++h) {
      bf16x8 af[4], bfr[4];
#pragma unroll
      for (int m = 0; m < 4; ++m) af[m] = *(const bf16x8*)&Ab[aoff[h][m]];
#pragma unroll
      for (int n = 0; n < 4; ++n) bfr[n] = *(const bf16x8*)&Bb[boff[h][n]];
#pragma unroll
      for (int m = 0; m < 4; ++m)
#pragma unroll
        for (int n = 0; n < 4; ++n)
          acc[m][n] = __builtin_amdgcn_mfma_f32_16x16x32_bf16(af[m], bfr[n], acc[m][n], 0, 0, 0);
    }
    __builtin_amdgcn_s_barrier();       // all waves done reading before re-stage
  }

  // Epilogue: C/D layout col = lane&15, row = (lane>>4)*4 + reg. Bias + scatter.
  const int colb = n0 + wc * 64 + (lane & 15);
  float bias[4];
#pragma unroll
  for (int n = 0; n < 4; ++n) bias[n] = eb[(e << 10) + colb + n * 16];
#pragma unroll
  for (int m = 0; m < 4; ++m) {
    int rbase = t * 128 + wr * 64 + m * 16 + ((lane >> 4) << 2);
#pragma unroll
    for (int r = 0; r < 4; ++r) {
      int mm = rbase + r;
      if (mm < c) {
        int g = tok[mm];
        float* op = out + ((size_t)g << 10);
#pragma unroll
        for (int n = 0; n < 4; ++n) op[colb + n * 16] = acc[m][n][r] + bias[n];
      }
    }
  }
}

extern "C" void kernel_launch(void* const* d_in, const int* in_sizes, int n_in,
                              void* d_out, int out_size, void* d_ws, size_t ws_size,
                              hipStream_t stream) {
  const float* x  = (const float*)d_in[0];
  const float* rw = (const float*)d_in[1];
  const float* rb = (const float*)d_in[2];
  const float* ew = (const float*)d_in[3];
  const float* eb = (const float*)d_in[4];
  float* out = (float*)d_out;

  char* ws = (char*)d_ws;
  unsigned short* wbf = (unsigned short*)ws;                         // 16 MB
  unsigned short* xbf = (unsigned short*)(ws + (16u << 20));         // 32 MB
  int* tok    = (int*)(ws + (48u << 20));                            // 512 KB
  int* counts = (int*)(ws + (48u << 20) + (1u << 19));               // 32 B
  int* top    = (int*)(ws + (48u << 20) + (1u << 19) + 128);         // 64 KB

  k_convw<<<4096, 256, 0, stream>>>(ew, wbf);
  k_router<<<NTOK / 16, 256, 0, stream>>>(x, rw, rb, xbf, top);      // 1024 blocks
  k_sort<<<1, 1024, 0, stream>>>(top, counts, tok);
  k_gemm<<<8192, 256, 0, stream>>>(xbf, wbf, eb, counts, tok, out);
}

// Round 9
// 131.817 us; speedup vs baseline: 2.7390x; 2.7390x over previous
//
#include <hip/hip_runtime.h>
#include <hip/hip_bf16.h>

// MoE top-1: N=16384 tokens, D=1024, E=8 experts.
// out[n] = expert_w[argmax(router(x[n]))] @ x[n] + expert_b[e]
//
// Pipeline: convw -> router (rw in LDS, token-pair ILP, f64 in-lane dots +
// f32 cross-lane reduce, fused x->bf16, no atomics, NO forced VGPR cap) ->
// single-block counting sort -> grouped bf16-MFMA GEMM (dbuf LDS, counted
// vmcnt, raw s_barrier, expert->XCD swizzle).

#define NTOK 16384
#define DIM  1024
#define NEXP 8

typedef __bf16 bf16x8 __attribute__((ext_vector_type(8)));
typedef float  f32x4  __attribute__((ext_vector_type(4)));

__device__ __forceinline__ unsigned int f2bf(float f) {
  unsigned int u = __builtin_bit_cast(unsigned int, f);
  u += 0x7FFFu + ((u >> 16) & 1u);   // round-to-nearest-even (finite inputs)
  return u >> 16;
}

// expert_w f32 -> bf16, 8 elements per thread. grid 4096 x 256.
__global__ __launch_bounds__(256) void k_convw(const float* __restrict__ src,
                                               unsigned short* __restrict__ dst) {
  size_t i = ((size_t)blockIdx.x * 256 + threadIdx.x) * 8;
  const float4* p = (const float4*)(src + i);
  float4 a = p[0], b = p[1];
  unsigned int w0 = f2bf(a.x) | (f2bf(a.y) << 16);
  unsigned int w1 = f2bf(a.z) | (f2bf(a.w) << 16);
  unsigned int w2 = f2bf(b.x) | (f2bf(b.y) << 16);
  unsigned int w3 = f2bf(b.z) | (f2bf(b.w) << 16);
  *(uint4*)(dst + i) = make_uint4(w0, w1, w2, w3);
}

// Router: rw (32 KB) staged in LDS once per block. Lane l owns x elements
// {j*256 + 4l .. +4}, j=0..3 (16 elems; 16 B/lane stride => conflict-free
// ds_read_b128, full LDS BW). TWO tokens per w-fragment read (w LDS traffic
// halved, two independent FMA chains). In-lane partials accumulate in f64
// (f32 products exact => dot ground-truth); cross-lane reduce in f32 (error
// ~3e-7 << np's own f32 noise). Reduce: xor{1,2,4} on 8 partials -> static
// select expert lane&7 (rule #20) -> xor{8,16,32} -> +bias -> argmax
// xor{1,2,4}, first index on ties. Fused x->bf16 (uint2/lane/chunk,
// coalesced). No atomics. NO min-waves bound: R8's (256,4) forced a 64-VGPR
// cap -> f64 accs spilled to scratch -> 700 MB of HBM scratch traffic.
__global__ __launch_bounds__(256) void k_router(const float* __restrict__ x,
                                                const float* __restrict__ rw,
                                                const float* __restrict__ rb,
                                                unsigned short* __restrict__ xbf,
                                                int* __restrict__ top) {
  __shared__ float wlds[NEXP * DIM];   // 32 KB
  const int tid = threadIdx.x;
  const int lane = tid & 63;
  const int wave = tid >> 6;
#pragma unroll
  for (int i = 0; i < 8; ++i)
    ((float4*)wlds)[tid + 256 * i] = ((const float4*)rw)[tid + 256 * i];
  __syncthreads();

  const int ea = lane & 7;
  const float bias = rb[ea];

#pragma unroll 1
  for (int tp = 0; tp < 2; ++tp) {     // two token-pairs per wave (4 tokens)
    const int nA = (blockIdx.x << 4) + (wave << 2) + (tp << 1);
    const int nB = nA + 1;

    float4 xa[4], xb[4];
#pragma unroll
    for (int j = 0; j < 4; ++j) {
      xa[j] = *(const float4*)(x + ((size_t)nA << 10) + (j << 8) + (lane << 2));
      xb[j] = *(const float4*)(x + ((size_t)nB << 10) + (j << 8) + (lane << 2));
    }

    // fused bf16 conversion + store: 8 B/lane per (token,j), coalesced 512 B
#pragma unroll
    for (int j = 0; j < 4; ++j) {
      uint2 sa, sb;
      sa.x = f2bf(xa[j].x) | (f2bf(xa[j].y) << 16);
      sa.y = f2bf(xa[j].z) | (f2bf(xa[j].w) << 16);
      sb.x = f2bf(xb[j].x) | (f2bf(xb[j].y) << 16);
      sb.y = f2bf(xb[j].z) | (f2bf(xb[j].w) << 16);
      *(uint2*)(xbf + ((size_t)nA << 10) + (j << 8) + (lane << 2)) = sa;
      *(uint2*)(xbf + ((size_t)nB << 10) + (j << 8) + (lane << 2)) = sb;
    }

    double pA[8] = {}, pB[8] = {};
#pragma unroll
    for (int e = 0; e < 8; ++e)
#pragma unroll
      for (int j = 0; j < 4; ++j) {
        float4 wv = *(const float4*)&wlds[e * 1024 + (j << 8) + (lane << 2)];
        pA[e] += (double)xa[j].x * (double)wv.x;
        pA[e] += (double)xa[j].y * (double)wv.y;
        pA[e] += (double)xa[j].z * (double)wv.z;
        pA[e] += (double)xa[j].w * (double)wv.w;
        pB[e] += (double)xb[j].x * (double)wv.x;
        pB[e] += (double)xb[j].y * (double)wv.y;
        pB[e] += (double)xb[j].z * (double)wv.z;
        pB[e] += (double)xb[j].w * (double)wv.w;
      }

    // f32 cross-lane reduce (two independent chains interleave)
    float qA[8], qB[8];
#pragma unroll
    for (int e = 0; e < 8; ++e) { qA[e] = (float)pA[e]; qB[e] = (float)pB[e]; }
#pragma unroll
    for (int e = 0; e < 8; ++e) {
      qA[e] += __shfl_xor(qA[e], 1);
      qB[e] += __shfl_xor(qB[e], 1);
      qA[e] += __shfl_xor(qA[e], 2);
      qB[e] += __shfl_xor(qB[e], 2);
      qA[e] += __shfl_xor(qA[e], 4);
      qB[e] += __shfl_xor(qB[e], 4);
    }
    // static select tree: s = q[ea] without runtime indexing (rule #20)
    float sA, sB;
    {
      float q0 = (ea & 1) ? qA[1] : qA[0], q1 = (ea & 1) ? qA[3] : qA[2];
      float q2 = (ea & 1) ? qA[5] : qA[4], q3 = (ea & 1) ? qA[7] : qA[6];
      float r0 = (ea & 2) ? q1 : q0, r1 = (ea & 2) ? q3 : q2;
      sA = (ea & 4) ? r1 : r0;
      q0 = (ea & 1) ? qB[1] : qB[0]; q1 = (ea & 1) ? qB[3] : qB[2];
      q2 = (ea & 1) ? qB[5] : qB[4]; q3 = (ea & 1) ? qB[7] : qB[6];
      r0 = (ea & 2) ? q1 : q0; r1 = (ea & 2) ? q3 : q2;
      sB = (ea & 4) ? r1 : r0;
    }
    sA += __shfl_xor(sA, 8);  sB += __shfl_xor(sB, 8);
    sA += __shfl_xor(sA, 16); sB += __shfl_xor(sB, 16);
    sA += __shfl_xor(sA, 32); sB += __shfl_xor(sB, 32);
    sA += bias; sB += bias;
    // argmax over experts (lane bits 0-2); first index on ties (np.argmax)
    float bvA = sA, bvB = sB;
    int biA = ea, biB = ea;
#pragma unroll
    for (int mask = 1; mask <= 4; mask <<= 1) {
      float ovA = __shfl_xor(bvA, mask), ovB = __shfl_xor(bvB, mask);
      int oiA = __shfl_xor(biA, mask), oiB = __shfl_xor(biB, mask);
      if (ovA > bvA || (ovA == bvA && oiA < biA)) { bvA = ovA; biA = oiA; }
      if (ovB > bvB || (ovB == bvB && oiB < biB)) { bvB = ovB; biB = oiB; }
    }
    if (lane == 0) {
      top[nA] = biA;
      top[nB] = biB;
    }
  }
}

// Counting sort of 16384 expert ids in ONE block (1024 threads x 16 tokens).
// Per-thread histogram packed as 2x u64 (8 experts x 16-bit fields); Hillis-
// Steele scan over packed u64s in LDS; ordered scatter into per-expert lists.
// Deterministic; lists sorted by token index (GEMM gather locality).
__global__ __launch_bounds__(1024) void k_sort(const int* __restrict__ top,
                                               int* __restrict__ counts,
                                               int* __restrict__ tok) {
  __shared__ unsigned long long sc[2][2][1024];  // 32 KB
  const int t = threadIdx.x;

  int4 v[4];
  const int4* tp = (const int4*)(top + t * 16);
#pragma unroll
  for (int i = 0; i < 4; ++i) v[i] = tp[i];

  unsigned long long h0 = 0, h1 = 0;
#pragma unroll
  for (int i = 0; i < 16; ++i) {
    int e = ((const int*)v)[i];
    if (e < 4) h0 += 1ull << (16 * e);
    else       h1 += 1ull << (16 * (e - 4));
  }
  sc[0][0][t] = h0;
  sc[0][1][t] = h1;
  __syncthreads();

  int cur = 0;
  for (int s = 1; s < 1024; s <<= 1) {
    unsigned long long a0 = sc[cur][0][t], a1 = sc[cur][1][t];
    if (t >= s) { a0 += sc[cur][0][t - s]; a1 += sc[cur][1][t - s]; }
    sc[cur ^ 1][0][t] = a0;
    sc[cur ^ 1][1][t] = a1;
    cur ^= 1;
    __syncthreads();
  }

  unsigned long long b0 = sc[cur][0][t] - h0;
  unsigned long long b1 = sc[cur][1][t] - h1;
  if (t == 1023) {
    unsigned long long i0 = sc[cur][0][t], i1 = sc[cur][1][t];
#pragma unroll
    for (int e = 0; e < 4; ++e) counts[e] = (int)((i0 >> (16 * e)) & 0xFFFF);
#pragma unroll
    for (int e = 0; e < 4; ++e) counts[4 + e] = (int)((i1 >> (16 * e)) & 0xFFFF);
  }
#pragma unroll
  for (int i = 0; i < 16; ++i) {
    int e = ((const int*)v)[i];
    int pos;
    if (e < 4) {
      pos = (int)((b0 >> (16 * e)) & 0xFFFF);
      b0 += 1ull << (16 * e);
    } else {
      int f = e - 4;
      pos = (int)((b1 >> (16 * f)) & 0xFFFF);
      b1 += 1ull << (16 * f);
    }
    tok[(e << 14) + pos] = t * 16 + i;
  }
}

// Grouped GEMM: C[m,o] = sum_d Xg[m,d] * W[o,d]. 128x128 tile, BK=64, 4 waves,
// mfma_f32_16x16x32_bf16. Double-buffered LDS staging with counted vmcnt and
// raw s_barrier (no vmcnt(0) drain in the main loop — T3+T4 pattern).
// 1D grid 8192, swizzled: xcd = bid&7 = expert; within an XCD, col-tile varies
// fastest so W_e (2 MB) and the current X token-tile stay L2-resident.
__global__ __launch_bounds__(256, 2) void k_gemm(const unsigned short* __restrict__ xbf,
                                                 const unsigned short* __restrict__ wbf,
                                                 const float* __restrict__ eb,
                                                 const int* __restrict__ counts,
                                                 const int* __restrict__ tokall,
                                                 float* __restrict__ out) {
  const int bid = blockIdx.x;          // 0..8191
  const int e = bid & 7;               // expert == XCD (dispatch round-robins %8)
  const int loc = bid >> 3;            // 0..1023 within XCD
  const int cb = loc & 7;              // col tile (fastest -> temporal locality)
  const int t = loc >> 3;              // token tile 0..127
  const int c = counts[e];
  if (t * 128 >= c) return;
  const int n0 = cb << 7;
  const int* tok = tokall + (e << 14);
  const int tid = threadIdx.x;
  const int lane = tid & 63;
  const int wave = tid >> 6;

  __shared__ unsigned short As[2][128 * 64];  // 2 x 16 KB, chunk-swizzled
  __shared__ unsigned short Bs[2][128 * 64];

  // Staging addresses: 4 x (32 rows x 8 chunks of 16B) per buffer. LDS dest is
  // linear (global_load_lds requirement); swizzle on the GLOBAL source side:
  // physical chunk p at row r holds logical chunk p ^ (r & 7).
  const int prow = tid >> 3;
  const int pchk = tid & 7;
  size_t asrc[4], bsrc[4];
  const unsigned short* wb = wbf + ((size_t)e << 20);
#pragma unroll
  for (int s = 0; s < 4; ++s) {
    int row = s * 32 + prow;
    int m = t * 128 + row;
    int g = tok[(m < c) ? m : 0];          // pad rows replay token 0 (stores guarded)
    int l = pchk ^ (row & 7);
    asrc[s] = (size_t)g * DIM + (size_t)l * 8;
    bsrc[s] = (size_t)(n0 + row) * DIM + (size_t)l * 8;
  }

  f32x4 acc[4][4] = {};
  const int wr = wave >> 1, wc = wave & 1;

  // LDS read offsets (elements). A-frag: lane holds A[row = lane&15][k = (lane>>4)*8 + j].
  int aoff[2][4], boff[2][4];
#pragma unroll
  for (int h = 0; h < 2; ++h)
#pragma unroll
    for (int m = 0; m < 4; ++m) {
      int row = wr * 64 + m * 16 + (lane & 15);
      int p = (h * 4 + (lane >> 4)) ^ (row & 7);
      aoff[h][m] = row * 64 + p * 8;
      int rowb = wc * 64 + m * 16 + (lane & 15);
      int pb = (h * 4 + (lane >> 4)) ^ (rowb & 7);
      boff[h][m] = rowb * 64 + pb * 8;
    }

  // stage one K-tile (8 global_load_lds of 16B per thread) into buffer b
  auto stage = [&](int b, int k0) {
#pragma unroll
    for (int s = 0; s < 4; ++s) {
      __builtin_amdgcn_global_load_lds(
          (const __attribute__((address_space(1))) unsigned int*)(xbf + asrc[s] + k0),
          (__attribute__((address_space(3))) unsigned int*)(&As[b][s * 2048 + wave * 512]),
          16, 0, 0);
      __builtin_amdgcn_global_load_lds(
          (const __attribute__((address_space(1))) unsigned int*)(wb + bsrc[s] + k0),
          (__attribute__((address_space(3))) unsigned int*)(&Bs[b][s * 2048 + wave * 512]),
          16, 0, 0);
    }
  };

  stage(0, 0);                          // 8 loads in flight
  for (int k = 0; k < 16; ++k) {
    if (k < 15) {
      stage((k + 1) & 1, (k + 1) * 64); // 16 in flight
      asm volatile("s_waitcnt vmcnt(8)" ::: "memory");  // current tile landed
    } else {
      asm volatile("s_waitcnt vmcnt(0)" ::: "memory");
    }
    __builtin_amdgcn_s_barrier();       // raw barrier: no compiler vmcnt(0) drain
    __builtin_amdgcn_sched_barrier(0);
    const unsigned short* Ab = As[k & 1];
    const unsigned short* Bb = Bs[k & 1];
#pragma unroll
    for (int h = 0; h < 2; ++h) {
      bf16x8 af[4], bfr[4];
#pragma unroll
      for (int m = 0; m < 4; ++m) af[m] = *(const bf16x8*)&Ab[aoff[h][m]];
#pragma unroll
      for (int n = 0; n < 4; ++n) bfr[n] = *(const bf16x8*)&Bb[boff[h][n]];
#pragma unroll
      for (int m = 0; m < 4; ++m)
#pragma unroll
        for (int n = 0; n < 4; ++n)
          acc[m][n] = __builtin_amdgcn_mfma_f32_16x16x32_bf16(af[m], bfr[n], acc[m][n], 0, 0, 0);
    }
    __builtin_amdgcn_s_barrier();       // all waves done reading before re-stage
  }

  // Epilogue: C/D layout col = lane&15, row = (lane>>4)*4 + reg. Bias + scatter.
  const int colb = n0 + wc * 64 + (lane & 15);
  float bias[4];
#pragma unroll
  for (int n = 0; n < 4; ++n) bias[n] = eb[(e << 10) + colb + n * 16];
#pragma unroll
  for (int m = 0; m < 4; ++m) {
    int rbase = t * 128 + wr * 64 + m * 16 + ((lane >> 4) << 2);
#pragma unroll
    for (int r = 0; r < 4; ++r) {
      int mm = rbase + r;
      if (mm < c) {
        int g = tok[mm];
        float* op = out + ((size_t)g << 10);
#pragma unroll
        for (int n = 0; n < 4; ++n) op[colb + n * 16] = acc[m][n][r] + bias[n];
      }
    }
  }
}

extern "C" void kernel_launch(void* const* d_in, const int* in_sizes, int n_in,
                              void* d_out, int out_size, void* d_ws, size_t ws_size,
                              hipStream_t stream) {
  const float* x  = (const float*)d_in[0];
  const float* rw = (const float*)d_in[1];
  const float* rb = (const float*)d_in[2];
  const float* ew = (const float*)d_in[3];
  const float* eb = (const float*)d_in[4];
  float* out = (float*)d_out;

  char* ws = (char*)d_ws;
  unsigned short* wbf = (unsigned short*)ws;                         // 16 MB
  unsigned short* xbf = (unsigned short*)(ws + (16u << 20));         // 32 MB
  int* tok    = (int*)(ws + (48u << 20));                            // 512 KB
  int* counts = (int*)(ws + (48u << 20) + (1u << 19));               // 32 B
  int* top    = (int*)(ws + (48u << 20) + (1u << 19) + 128);         // 64 KB

  k_convw<<<4096, 256, 0, stream>>>(ew, wbf);
  k_router<<<NTOK / 16, 256, 0, stream>>>(x, rw, rb, xbf, top);      // 1024 blocks
  k_sort<<<1, 1024, 0, stream>>>(top, counts, tok);
  k_gemm<<<8192, 256, 0, stream>>>(xbf, wbf, eb, counts, tok, out);
}

// Round 10
// 113.470 us; speedup vs baseline: 3.1819x; 1.1617x over previous
//
#include <hip/hip_runtime.h>
#include <hip/hip_bf16.h>

// MoE top-1: N=16384 tokens, D=1024, E=8 experts.
// out[n] = expert_w[argmax(router(x[n]))] @ x[n] + expert_b[e]
//
// Pipeline: convw -> router (rw in LDS, token-pair ILP, j-outer/e-inner with
// sched_barrier to cap VGPR, f64 in-lane dots + f32 cross-lane reduce, fused
// x->bf16, no atomics) -> single-block counting sort -> grouped bf16-MFMA
// GEMM (BK=32 dbuf = 32 KB LDS -> 5 blocks/CU, counted vmcnt, raw s_barrier,
// expert->XCD swizzle).

#define NTOK 16384
#define DIM  1024
#define NEXP 8

typedef __bf16 bf16x8 __attribute__((ext_vector_type(8)));
typedef float  f32x4  __attribute__((ext_vector_type(4)));

__device__ __forceinline__ unsigned int f2bf(float f) {
  unsigned int u = __builtin_bit_cast(unsigned int, f);
  u += 0x7FFFu + ((u >> 16) & 1u);   // round-to-nearest-even (finite inputs)
  return u >> 16;
}

// expert_w f32 -> bf16, 8 elements per thread. grid 4096 x 256.
__global__ __launch_bounds__(256) void k_convw(const float* __restrict__ src,
                                               unsigned short* __restrict__ dst) {
  size_t i = ((size_t)blockIdx.x * 256 + threadIdx.x) * 8;
  const float4* p = (const float4*)(src + i);
  float4 a = p[0], b = p[1];
  unsigned int w0 = f2bf(a.x) | (f2bf(a.y) << 16);
  unsigned int w1 = f2bf(a.z) | (f2bf(a.w) << 16);
  unsigned int w2 = f2bf(b.x) | (f2bf(b.y) << 16);
  unsigned int w3 = f2bf(b.z) | (f2bf(b.w) << 16);
  *(uint4*)(dst + i) = make_uint4(w0, w1, w2, w3);
}

// Router: rw (32 KB) staged in LDS once per block. Lane l owns x elements
// {j*256 + 4l .. +4}, j=0..3 (16 B/lane stride => conflict-free ds_read_b128).
// TWO tokens per w-fragment read. j-OUTER / e-INNER with a sched_barrier(0)
// after each j: caps live w-fragments at ~8 VGPRs (R9's e-outer nest let the
// scheduler hoist ~28 b128 loads -> 192 VGPR -> 2 waves/SIMD -> 65 us).
// In-lane partials in f64 (f32 products exact => argmax ground-truth);
// cross-lane reduce in f32 (err ~3e-7 << np's own f32 noise). Fused x->bf16.
__global__ __launch_bounds__(256) void k_router(const float* __restrict__ x,
                                                const float* __restrict__ rw,
                                                const float* __restrict__ rb,
                                                unsigned short* __restrict__ xbf,
                                                int* __restrict__ top) {
  __shared__ float wlds[NEXP * DIM];   // 32 KB
  const int tid = threadIdx.x;
  const int lane = tid & 63;
  const int wave = tid >> 6;
#pragma unroll
  for (int i = 0; i < 8; ++i)
    ((float4*)wlds)[tid + 256 * i] = ((const float4*)rw)[tid + 256 * i];
  __syncthreads();

  const int ea = lane & 7;
  const float bias = rb[ea];

#pragma unroll 1
  for (int tp = 0; tp < 2; ++tp) {     // two token-pairs per wave (4 tokens)
    const int nA = (blockIdx.x << 4) + (wave << 2) + (tp << 1);
    const int nB = nA + 1;

    float4 xa[4], xb[4];
#pragma unroll
    for (int j = 0; j < 4; ++j) {      // 8 independent 16B loads (deep MLP)
      xa[j] = *(const float4*)(x + ((size_t)nA << 10) + (j << 8) + (lane << 2));
      xb[j] = *(const float4*)(x + ((size_t)nB << 10) + (j << 8) + (lane << 2));
    }

    // fused bf16 conversion + store: 8 B/lane per (token,j), coalesced 512 B
#pragma unroll
    for (int j = 0; j < 4; ++j) {
      uint2 sa, sb;
      sa.x = f2bf(xa[j].x) | (f2bf(xa[j].y) << 16);
      sa.y = f2bf(xa[j].z) | (f2bf(xa[j].w) << 16);
      sb.x = f2bf(xb[j].x) | (f2bf(xb[j].y) << 16);
      sb.y = f2bf(xb[j].z) | (f2bf(xb[j].w) << 16);
      *(uint2*)(xbf + ((size_t)nA << 10) + (j << 8) + (lane << 2)) = sa;
      *(uint2*)(xbf + ((size_t)nB << 10) + (j << 8) + (lane << 2)) = sb;
    }

    double pA[8] = {}, pB[8] = {};
#pragma unroll
    for (int j = 0; j < 4; ++j) {
#pragma unroll
      for (int e = 0; e < 8; ++e) {
        float4 wv = *(const float4*)&wlds[e * 1024 + (j << 8) + (lane << 2)];
        pA[e] += (double)xa[j].x * (double)wv.x;
        pA[e] += (double)xa[j].y * (double)wv.y;
        pA[e] += (double)xa[j].z * (double)wv.z;
        pA[e] += (double)xa[j].w * (double)wv.w;
        pB[e] += (double)xb[j].x * (double)wv.x;
        pB[e] += (double)xb[j].y * (double)wv.y;
        pB[e] += (double)xb[j].z * (double)wv.z;
        pB[e] += (double)xb[j].w * (double)wv.w;
      }
      __builtin_amdgcn_sched_barrier(0);   // stop cross-j w-load hoisting
    }

    // f32 cross-lane reduce (two independent chains interleave)
    float qA[8], qB[8];
#pragma unroll
    for (int e = 0; e < 8; ++e) { qA[e] = (float)pA[e]; qB[e] = (float)pB[e]; }
#pragma unroll
    for (int e = 0; e < 8; ++e) {
      qA[e] += __shfl_xor(qA[e], 1);
      qB[e] += __shfl_xor(qB[e], 1);
      qA[e] += __shfl_xor(qA[e], 2);
      qB[e] += __shfl_xor(qB[e], 2);
      qA[e] += __shfl_xor(qA[e], 4);
      qB[e] += __shfl_xor(qB[e], 4);
    }
    // static select tree: s = q[ea] without runtime indexing (rule #20)
    float sA, sB;
    {
      float q0 = (ea & 1) ? qA[1] : qA[0], q1 = (ea & 1) ? qA[3] : qA[2];
      float q2 = (ea & 1) ? qA[5] : qA[4], q3 = (ea & 1) ? qA[7] : qA[6];
      float r0 = (ea & 2) ? q1 : q0, r1 = (ea & 2) ? q3 : q2;
      sA = (ea & 4) ? r1 : r0;
      q0 = (ea & 1) ? qB[1] : qB[0]; q1 = (ea & 1) ? qB[3] : qB[2];
      q2 = (ea & 1) ? qB[5] : qB[4]; q3 = (ea & 1) ? qB[7] : qB[6];
      r0 = (ea & 2) ? q1 : q0; r1 = (ea & 2) ? q3 : q2;
      sB = (ea & 4) ? r1 : r0;
    }
    sA += __shfl_xor(sA, 8);  sB += __shfl_xor(sB, 8);
    sA += __shfl_xor(sA, 16); sB += __shfl_xor(sB, 16);
    sA += __shfl_xor(sA, 32); sB += __shfl_xor(sB, 32);
    sA += bias; sB += bias;
    // argmax over experts (lane bits 0-2); first index on ties (np.argmax)
    float bvA = sA, bvB = sB;
    int biA = ea, biB = ea;
#pragma unroll
    for (int mask = 1; mask <= 4; mask <<= 1) {
      float ovA = __shfl_xor(bvA, mask), ovB = __shfl_xor(bvB, mask);
      int oiA = __shfl_xor(biA, mask), oiB = __shfl_xor(biB, mask);
      if (ovA > bvA || (ovA == bvA && oiA < biA)) { bvA = ovA; biA = oiA; }
      if (ovB > bvB || (ovB == bvB && oiB < biB)) { bvB = ovB; biB = oiB; }
    }
    if (lane == 0) {
      top[nA] = biA;
      top[nB] = biB;
    }
  }
}

// Counting sort of 16384 expert ids in ONE block (1024 threads x 16 tokens).
// Per-thread histogram packed as 2x u64 (8 experts x 16-bit fields); Hillis-
// Steele scan over packed u64s in LDS; ordered scatter into per-expert lists.
// Deterministic; lists sorted by token index (GEMM gather locality).
__global__ __launch_bounds__(1024) void k_sort(const int* __restrict__ top,
                                               int* __restrict__ counts,
                                               int* __restrict__ tok) {
  __shared__ unsigned long long sc[2][2][1024];  // 32 KB
  const int t = threadIdx.x;

  int4 v[4];
  const int4* tp = (const int4*)(top + t * 16);
#pragma unroll
  for (int i = 0; i < 4; ++i) v[i] = tp[i];

  unsigned long long h0 = 0, h1 = 0;
#pragma unroll
  for (int i = 0; i < 16; ++i) {
    int e = ((const int*)v)[i];
    if (e < 4) h0 += 1ull << (16 * e);
    else       h1 += 1ull << (16 * (e - 4));
  }
  sc[0][0][t] = h0;
  sc[0][1][t] = h1;
  __syncthreads();

  int cur = 0;
  for (int s = 1; s < 1024; s <<= 1) {
    unsigned long long a0 = sc[cur][0][t], a1 = sc[cur][1][t];
    if (t >= s) { a0 += sc[cur][0][t - s]; a1 += sc[cur][1][t - s]; }
    sc[cur ^ 1][0][t] = a0;
    sc[cur ^ 1][1][t] = a1;
    cur ^= 1;
    __syncthreads();
  }

  unsigned long long b0 = sc[cur][0][t] - h0;
  unsigned long long b1 = sc[cur][1][t] - h1;
  if (t == 1023) {
    unsigned long long i0 = sc[cur][0][t], i1 = sc[cur][1][t];
#pragma unroll
    for (int e = 0; e < 4; ++e) counts[e] = (int)((i0 >> (16 * e)) & 0xFFFF);
#pragma unroll
    for (int e = 0; e < 4; ++e) counts[4 + e] = (int)((i1 >> (16 * e)) & 0xFFFF);
  }
#pragma unroll
  for (int i = 0; i < 16; ++i) {
    int e = ((const int*)v)[i];
    int pos;
    if (e < 4) {
      pos = (int)((b0 >> (16 * e)) & 0xFFFF);
      b0 += 1ull << (16 * e);
    } else {
      int f = e - 4;
      pos = (int)((b1 >> (16 * f)) & 0xFFFF);
      b1 += 1ull << (16 * f);
    }
    tok[(e << 14) + pos] = t * 16 + i;
  }
}

// Grouped GEMM: C[m,o] = sum_d Xg[m,d] * W[o,d]. 128x128 tile, BK=32, 4 waves,
// mfma_f32_16x16x32_bf16 (one MFMA consumes the whole K-step). Double-buffered
// LDS = 32 KB/block -> ~5 blocks/CU (2.5x the BK=64 version's TLP). Counted
// vmcnt(4) + raw s_barrier: no vmcnt(0) drain in the main loop (T3+T4).
// Rows are 64 B => bank-slot swizzle chunk ^= (row ^ row>>2)&3 spreads the 64
// lanes uniformly over the 8 16B-slots (2-way max aliasing = free, m136).
// 1D grid 8192: xcd = bid&7 = expert; col-tile fastest within XCD (L2 reuse).
__global__ __launch_bounds__(256) void k_gemm(const unsigned short* __restrict__ xbf,
                                              const unsigned short* __restrict__ wbf,
                                              const float* __restrict__ eb,
                                              const int* __restrict__ counts,
                                              const int* __restrict__ tokall,
                                              float* __restrict__ out) {
  const int bid = blockIdx.x;          // 0..8191
  const int e = bid & 7;               // expert == XCD (dispatch round-robins %8)
  const int loc = bid >> 3;            // 0..1023 within XCD
  const int cb = loc & 7;              // col tile (fastest -> temporal locality)
  const int t = loc >> 3;              // token tile 0..127
  const int c = counts[e];
  if (t * 128 >= c) return;
  const int n0 = cb << 7;
  const int* tok = tokall + (e << 14);
  const int tid = threadIdx.x;
  const int lane = tid & 63;
  const int wave = tid >> 6;

  __shared__ unsigned short As[2][128 * 32];  // 2 x 8 KB
  __shared__ unsigned short Bs[2][128 * 32];  // 2 x 8 KB

  // Staging: 2 x (64 rows x 4 chunks of 16B) per matrix per buffer. LDS dest
  // is linear lane*16B (global_load_lds requirement); swizzle applied on the
  // GLOBAL source: physical chunk p at row r holds logical chunk p ^ rsw(r),
  // rsw(r) = (r ^ r>>2) & 3.
  const int prow = tid >> 2;           // 0..63
  const int pchk = tid & 3;            // 0..3
  size_t asrc[2], bsrc[2];
  const unsigned short* wb = wbf + ((size_t)e << 20);
#pragma unroll
  for (int s = 0; s < 2; ++s) {
    int row = s * 64 + prow;
    int m = t * 128 + row;
    int g = tok[(m < c) ? m : 0];          // pad rows replay token 0 (stores guarded)
    int l = pchk ^ ((row ^ (row >> 2)) & 3);
    asrc[s] = (size_t)g * DIM + (size_t)l * 8;
    bsrc[s] = (size_t)(n0 + row) * DIM + (size_t)l * 8;
  }

  f32x4 acc[4][4] = {};
  const int wr = wave >> 1, wc = wave & 1;

  // LDS read offsets (elements). A-frag: lane holds A[row = lane&15][k = (lane>>4)*8 + j].
  int aoff[4], boff[4];
#pragma unroll
  for (int m = 0; m < 4; ++m) {
    int row = wr * 64 + m * 16 + (lane & 15);
    int p = ((lane >> 4) ^ (row ^ (row >> 2))) & 3;
    aoff[m] = row * 32 + p * 8;
    int rowb = wc * 64 + m * 16 + (lane & 15);
    int pb = ((lane >> 4) ^ (rowb ^ (rowb >> 2))) & 3;
    boff[m] = rowb * 32 + pb * 8;
  }

  // stage one K-tile (4 global_load_lds of 16B per thread) into buffer b
  auto stage = [&](int b, int k0) {
#pragma unroll
    for (int s = 0; s < 2; ++s) {
      __builtin_amdgcn_global_load_lds(
          (const __attribute__((address_space(1))) unsigned int*)(xbf + asrc[s] + k0),
          (__attribute__((address_space(3))) unsigned int*)(&As[b][s * 2048 + wave * 512]),
          16, 0, 0);
      __builtin_amdgcn_global_load_lds(
          (const __attribute__((address_space(1))) unsigned int*)(wb + bsrc[s] + k0),
          (__attribute__((address_space(3))) unsigned int*)(&Bs[b][s * 2048 + wave * 512]),
          16, 0, 0);
    }
  };

  stage(0, 0);                          // 4 loads in flight
  for (int k = 0; k < 32; ++k) {
    if (k < 31) {
      stage((k + 1) & 1, (k + 1) * 32); // 8 in flight
      asm volatile("s_waitcnt vmcnt(4)" ::: "memory");  // current tile landed
    } else {
      asm volatile("s_waitcnt vmcnt(0)" ::: "memory");
    }
    __builtin_amdgcn_s_barrier();       // raw barrier: no compiler vmcnt(0) drain
    __builtin_amdgcn_sched_barrier(0);
    const unsigned short* Ab = As[k & 1];
    const unsigned short* Bb = Bs[k & 1];
    bf16x8 af[4], bfr[4];
#pragma unroll
    for (int m = 0; m < 4; ++m) af[m] = *(const bf16x8*)&Ab[aoff[m]];
#pragma unroll
    for (int n = 0; n < 4; ++n) bfr[n] = *(const bf16x8*)&Bb[boff[n]];
#pragma unroll
    for (int m = 0; m < 4; ++m)
#pragma unroll
      for (int n = 0; n < 4; ++n)
        acc[m][n] = __builtin_amdgcn_mfma_f32_16x16x32_bf16(af[m], bfr[n], acc[m][n], 0, 0, 0);
    __builtin_amdgcn_s_barrier();       // all waves done reading before re-stage
  }

  // Epilogue: C/D layout col = lane&15, row = (lane>>4)*4 + reg. Bias + scatter.
  const int colb = n0 + wc * 64 + (lane & 15);
  float bias[4];
#pragma unroll
  for (int n = 0; n < 4; ++n) bias[n] = eb[(e << 10) + colb + n * 16];
#pragma unroll
  for (int m = 0; m < 4; ++m) {
    int rbase = t * 128 + wr * 64 + m * 16 + ((lane >> 4) << 2);
#pragma unroll
    for (int r = 0; r < 4; ++r) {
      int mm = rbase + r;
      if (mm < c) {
        int g = tok[mm];
        float* op = out + ((size_t)g << 10);
#pragma unroll
        for (int n = 0; n < 4; ++n) op[colb + n * 16] = acc[m][n][r] + bias[n];
      }
    }
  }
}

extern "C" void kernel_launch(void* const* d_in, const int* in_sizes, int n_in,
                              void* d_out, int out_size, void* d_ws, size_t ws_size,
                              hipStream_t stream) {
  const float* x  = (const float*)d_in[0];
  const float* rw = (const float*)d_in[1];
  const float* rb = (const float*)d_in[2];
  const float* ew = (const float*)d_in[3];
  const float* eb = (const float*)d_in[4];
  float* out = (float*)d_out;

  char* ws = (char*)d_ws;
  unsigned short* wbf = (unsigned short*)ws;                         // 16 MB
  unsigned short* xbf = (unsigned short*)(ws + (16u << 20));         // 32 MB
  int* tok    = (int*)(ws + (48u << 20));                            // 512 KB
  int* counts = (int*)(ws + (48u << 20) + (1u << 19));               // 32 B
  int* top    = (int*)(ws + (48u << 20) + (1u << 19) + 128);         // 64 KB

  k_convw<<<4096, 256, 0, stream>>>(ew, wbf);
  k_router<<<NTOK / 16, 256, 0, stream>>>(x, rw, rb, xbf, top);      // 1024 blocks
  k_sort<<<1, 1024, 0, stream>>>(top, counts, tok);
  k_gemm<<<8192, 256, 0, stream>>>(xbf, wbf, eb, counts, tok, out);
}